// Round 4
// baseline (913.408 us; speedup 1.0000x reference)
//
#include <hip/hip_runtime.h>
#include <math.h>

// Problem dims
#define S_LEN 2048
#define D_HEAD 64
#define BH 32     // BS*H
#define CHUNK 8   // bh per chunk (scores footprint 134MB < 256MB LLC)
#define NCHUNK (BH / CHUNK)

typedef __attribute__((ext_vector_type(8))) short short8;    // 8 x bf16 bits
typedef __attribute__((ext_vector_type(16))) float f32x16;   // 32x32 MFMA acc
typedef __attribute__((ext_vector_type(4))) float f32x4;     // native vec for NT builtins

__device__ __forceinline__ short f2bf(float f) {
  union { float f; unsigned u; } a; a.f = f;
  unsigned u = a.u;
  unsigned r = (u + 0x7fffu + ((u >> 16) & 1u)) >> 16;   // RNE, no NaNs here
  return (short)r;
}
__device__ __forceinline__ float ntl(const float* p)  { return __builtin_nontemporal_load(p); }
__device__ __forceinline__ f32x4 ntl4(const float* p) { return __builtin_nontemporal_load((const f32x4*)p); }
__device__ __forceinline__ void  nts4(float* p, f32x4 v) { __builtin_nontemporal_store(v, (f32x4*)p); }

// ---------------------------------------------------------------------------
// Kernel T: K [bh][64][2048] -> kT [bh][2048][64] bf16 ; V [bh][2048][64] ->
// vT [bh][64][2048] bf16. Fully coalesced both sides; pad-65 LDS.
// ---------------------------------------------------------------------------
__global__ __launch_bounds__(256) void transpose_kernel(
    const float* __restrict__ kin, const float* __restrict__ vin,
    unsigned short* __restrict__ kT, unsigned short* __restrict__ vT)
{
  __shared__ float tile[64][65];
  const int bh = blockIdx.y;
  const int bx = blockIdx.x;
  const int t  = threadIdx.x;

  if (blockIdx.z == 0) {
    // K: in rows = d(64), cols = s ; tile covers s-block bx*64
    const float* in = kin + (size_t)bh * D_HEAD * S_LEN;
    #pragma unroll
    for (int p = 0; p < 4; ++p) {
      const int row = p * 16 + (t >> 4);
      f32x4 f = ntl4(in + (size_t)row * S_LEN + bx * 64 + (t & 15) * 4);
      tile[row][(t & 15) * 4 + 0] = f.x; tile[row][(t & 15) * 4 + 1] = f.y;
      tile[row][(t & 15) * 4 + 2] = f.z; tile[row][(t & 15) * 4 + 3] = f.w;
    }
    __syncthreads();
    union { unsigned short h[16]; uint4 q[2]; } u;
    #pragma unroll
    for (int i = 0; i < 16; ++i) u.h[i] = (unsigned short)f2bf(tile[(t & 3) * 16 + i][t >> 2]);
    uint4* dst = (uint4*)(kT + (size_t)bh * S_LEN * D_HEAD
                             + (size_t)(bx * 64 + (t >> 2)) * D_HEAD + (t & 3) * 16);
    dst[0] = u.q[0]; dst[1] = u.q[1];
  } else {
    // V: in rows = s (block bx*64), cols = d(64)
    const float* in = vin + (size_t)bh * S_LEN * D_HEAD;
    #pragma unroll
    for (int p = 0; p < 4; ++p) {
      const int row = p * 16 + (t >> 4);
      f32x4 f = ntl4(in + (size_t)(bx * 64 + row) * D_HEAD + (t & 15) * 4);
      tile[row][(t & 15) * 4 + 0] = f.x; tile[row][(t & 15) * 4 + 1] = f.y;
      tile[row][(t & 15) * 4 + 2] = f.z; tile[row][(t & 15) * 4 + 3] = f.w;
    }
    __syncthreads();
    union { unsigned short h[16]; uint4 q[2]; } u;
    #pragma unroll
    for (int i = 0; i < 16; ++i) u.h[i] = (unsigned short)f2bf(tile[(t & 3) * 16 + i][t >> 2]);
    uint4* dst = (uint4*)(vT + (size_t)bh * D_HEAD * S_LEN
                             + (size_t)(t >> 2) * S_LEN + bx * 64 + (t & 3) * 16);
    dst[0] = u.q[0]; dst[1] = u.q[1];
  }
}

// ---------------------------------------------------------------------------
// Kernel A (per chunk): scores = (Q@K)*scale + prev (f32, normal stores ->
// LLC-resident), ws_l = sum(exp(s)) per row (no max: |s| small, f32-safe).
// Block = 32-row strip, 4 waves column-split (512 cols each). 32x32x16 MFMA.
// prev loads NON-TEMPORAL (don't pollute LLC).
// ---------------------------------------------------------------------------
__global__ __launch_bounds__(256, 2) void scores_kernel(
    const float* __restrict__ q, const unsigned short* __restrict__ kT,
    const float* __restrict__ prev, const float* __restrict__ scale_p,
    float* __restrict__ scores, float* __restrict__ ws_l, int bh0)
{
  const int bh   = bh0 + blockIdx.y;
  const int m0   = blockIdx.x * 32;
  const int tid  = threadIdx.x;
  const int w    = tid >> 6;
  const int lane = tid & 63;
  const int l31  = lane & 31;
  const int hi   = lane >> 5;
  const float scale = scale_p[0];

  // A-frags: row = m0 + l31, k-elem j of chunk kk -> d = kk*16 + hi*8 + j
  short8 aq[4];
  const float* qrow = q + ((size_t)bh * S_LEN + m0 + l31) * D_HEAD;
  #pragma unroll
  for (int kk = 0; kk < 4; ++kk) {
    f32x4 f0 = *(const f32x4*)(qrow + kk * 16 + hi * 8);
    f32x4 f1 = *(const f32x4*)(qrow + kk * 16 + hi * 8 + 4);
    short8 a;
    a[0]=f2bf(f0.x); a[1]=f2bf(f0.y); a[2]=f2bf(f0.z); a[3]=f2bf(f0.w);
    a[4]=f2bf(f1.x); a[5]=f2bf(f1.y); a[6]=f2bf(f1.z); a[7]=f2bf(f1.w);
    aq[kk] = a;
  }

  float ls[16];
  #pragma unroll
  for (int r = 0; r < 16; ++r) ls[r] = 0.f;

  const unsigned short* kbase = kT + (size_t)bh * S_LEN * D_HEAD;
  const float* prow = prev   + (size_t)bh * S_LEN * S_LEN;
  float*       srow = scores + (size_t)bh * S_LEN * S_LEN;

  for (int t8 = 0; t8 < 8; ++t8) {
    const int n0 = w * 512 + t8 * 64;
    f32x16 acc[2];
    #pragma unroll
    for (int ct = 0; ct < 2; ++ct)
      #pragma unroll
      for (int r = 0; r < 16; ++r) acc[ct][r] = 0.f;

    #pragma unroll
    for (int kk = 0; kk < 4; ++kk) {
      #pragma unroll
      for (int ct = 0; ct < 2; ++ct) {
        const unsigned short* kp =
            kbase + (size_t)(n0 + ct * 32 + l31) * D_HEAD + kk * 16 + hi * 8;
        short8 b = *(const short8*)kp;
        acc[ct] = __builtin_amdgcn_mfma_f32_32x32x16_bf16(aq[kk], b, acc[ct], 0, 0, 0);
      }
    }

    #pragma unroll
    for (int r = 0; r < 16; ++r) {
      const int row = m0 + (r & 3) + 8 * (r >> 2) + 4 * hi;
      const size_t g = (size_t)row * S_LEN + n0 + l31;
      const float sv0 = acc[0][r] * scale + ntl(prow + g);
      const float sv1 = acc[1][r] * scale + ntl(prow + g + 32);
      srow[g]      = sv0;          // normal store: keep in LLC for pv
      srow[g + 32] = sv1;
      ls[r] += __expf(sv0) + __expf(sv1);
    }
  }

  // in-wave reduce (within 32-lane halves; masks <=16 stay in-half)
  #pragma unroll
  for (int r = 0; r < 16; ++r) {
    #pragma unroll
    for (int msk = 1; msk <= 16; msk <<= 1)
      ls[r] += __shfl_xor(ls[r], msk, 64);
  }
  __shared__ float lred[4][32];
  if (l31 == 0) {
    #pragma unroll
    for (int r = 0; r < 16; ++r)
      lred[w][(r & 3) + 8 * (r >> 2) + 4 * hi] = ls[r];
  }
  __syncthreads();
  if (tid < 32) {
    const float l = lred[0][tid] + lred[1][tid] + lred[2][tid] + lred[3][tid];
    ws_l[bh * S_LEN + m0 + tid] = l;
  }
}

// ---------------------------------------------------------------------------
// Kernel B (per chunk): weights = exp(s)/l (NT f32 stores), O = weights @ V.
// Block = 32-row strip, 4 waves: w>>1 = column half (1024 cols), w&1 = D half.
// Scores read normal (LLC hits from the just-finished scores chunk).
// Partial O merged across column halves via LDS.
// ---------------------------------------------------------------------------
__global__ __launch_bounds__(256, 2) void pv_kernel(
    const float* __restrict__ scores, const unsigned short* __restrict__ vT,
    const float* __restrict__ ws_l,
    float* __restrict__ weights, float* __restrict__ outO, int bh0)
{
  const int bh    = bh0 + blockIdx.y;
  const int m0    = blockIdx.x * 32;
  const int tid   = threadIdx.x;
  const int w     = tid >> 6;
  const int lane  = tid & 63;
  const int l31   = lane & 31;
  const int hi    = lane >> 5;
  const int khalf = w >> 1;   // column half of the 2048 K-range
  const int dhalf = w & 1;    // which 32 of D=64

  const float rl = 1.0f / ws_l[bh * S_LEN + m0 + l31];

  const float* srow = scores  + (size_t)bh * S_LEN * S_LEN + (size_t)(m0 + l31) * S_LEN;
  float*       wrow = weights + (size_t)bh * S_LEN * S_LEN + (size_t)(m0 + l31) * S_LEN;
  const unsigned short* vrow =
      vT + (size_t)bh * D_HEAD * S_LEN + (size_t)(dhalf * 32 + l31) * S_LEN;

  f32x16 acc;
  #pragma unroll
  for (int r = 0; r < 16; ++r) acc[r] = 0.f;

  for (int t16 = 0; t16 < 16; ++t16) {
    const int n0 = khalf * 1024 + t16 * 64;
    #pragma unroll
    for (int kk = 0; kk < 4; ++kk) {
      const int c = n0 + kk * 16 + hi * 8;
      const f32x4 fa = *(const f32x4*)(srow + c);
      const f32x4 fb = *(const f32x4*)(srow + c + 4);
      const float e0 = __expf(fa.x) * rl, e1 = __expf(fa.y) * rl;
      const float e2 = __expf(fa.z) * rl, e3 = __expf(fa.w) * rl;
      const float e4 = __expf(fb.x) * rl, e5 = __expf(fb.y) * rl;
      const float e6 = __expf(fb.z) * rl, e7 = __expf(fb.w) * rl;
      nts4(wrow + c,     (f32x4){e0, e1, e2, e3});
      nts4(wrow + c + 4, (f32x4){e4, e5, e6, e7});
      short8 a;
      a[0]=f2bf(e0); a[1]=f2bf(e1); a[2]=f2bf(e2); a[3]=f2bf(e3);
      a[4]=f2bf(e4); a[5]=f2bf(e5); a[6]=f2bf(e6); a[7]=f2bf(e7);
      const short8 b = *(const short8*)(vrow + c);
      acc = __builtin_amdgcn_mfma_f32_32x32x16_bf16(a, b, acc, 0, 0, 0);
    }
  }

  // merge column halves, store O coalesced
  __shared__ float ored[2][2][32][33];
  #pragma unroll
  for (int r = 0; r < 16; ++r)
    ored[khalf][dhalf][(r & 3) + 8 * (r >> 2) + 4 * hi][l31] = acc[r];
  __syncthreads();

  const int row = tid >> 3;
  const int c8  = (tid & 7) * 8;
  const int dh  = c8 >> 5;
  const int cw  = c8 & 31;
  float v[8];
  #pragma unroll
  for (int i = 0; i < 8; ++i)
    v[i] = ored[0][dh][row][cw + i] + ored[1][dh][row][cw + i];
  float* op = outO + ((size_t)bh * S_LEN + m0 + row) * D_HEAD + c8;
  nts4(op,     (f32x4){v[0], v[1], v[2], v[3]});
  nts4(op + 4, (f32x4){v[4], v[5], v[6], v[7]});
}

// ---------------------------------------------------------------------------
extern "C" void kernel_launch(void* const* d_in, const int* in_sizes, int n_in,
                              void* d_out, int out_size, void* d_ws, size_t ws_size,
                              hipStream_t stream)
{
  const float* q     = (const float*)d_in[0];
  const float* kin   = (const float*)d_in[1];
  const float* vin   = (const float*)d_in[2];
  const float* prev  = (const float*)d_in[3];
  const float* scale = (const float*)d_in[4];

  float* O  = (float*)d_out;                                  // [32][2048][64]
  float* W  = O + (size_t)BH * S_LEN * D_HEAD;                // [32][2048][2048]
  float* Sc = W + (size_t)BH * S_LEN * S_LEN;                 // [32][2048][2048]

  unsigned short* kT = (unsigned short*)d_ws;                 // [32][2048][64] bf16
  unsigned short* vT = kT + (size_t)BH * S_LEN * D_HEAD;      // [32][64][2048] bf16
  float* ws_l = (float*)(vT + (size_t)BH * S_LEN * D_HEAD);   // [32][2048]

  dim3 tgrid(S_LEN / 64, BH, 2);
  hipLaunchKernelGGL(transpose_kernel, tgrid, dim3(256), 0, stream, kin, vin, kT, vT);

  // chunked interleave: pv(c) re-reads scores(c) while they are LLC-resident
  for (int c = 0; c < NCHUNK; ++c) {
    dim3 grid(S_LEN / 32, CHUNK);
    hipLaunchKernelGGL(scores_kernel, grid, dim3(256), 0, stream,
                       q, kT, prev, scale, Sc, ws_l, c * CHUNK);
    hipLaunchKernelGGL(pv_kernel, grid, dim3(256), 0, stream,
                       Sc, vT, ws_l, W, O, c * CHUNK);
  }
}

// Round 5
// 566.004 us; speedup vs baseline: 1.6138x; 1.6138x over previous
//
#include <hip/hip_runtime.h>
#include <math.h>

// Problem dims
#define S_LEN 2048
#define D_HEAD 64
#define BH 32

typedef __attribute__((ext_vector_type(8))) short short8;    // 8 bf16 (4 VGPR)
typedef __attribute__((ext_vector_type(4))) short short4v;   // 8B LDS chunk
typedef __attribute__((ext_vector_type(4))) float f32x4;

#define SPAD 2052   // LDS row stride in bf16: 4104B = 8B-aligned, bank stride 2 -> 2-way (free)

__device__ __forceinline__ short f2bf(float f) {
  union { float f; unsigned u; } a; a.f = f;
  unsigned u = a.u;
  unsigned r = (u + 0x7fffu + ((u >> 16) & 1u)) >> 16;   // RNE, no NaNs here
  return (short)r;
}
__device__ __forceinline__ float bf2f(unsigned short h) {
  union { unsigned u; float f; } a; a.u = ((unsigned)h) << 16; return a.f;
}
__device__ __forceinline__ float ntl(const float* p)  { return __builtin_nontemporal_load(p); }
__device__ __forceinline__ f32x4 ntl4(const float* p) { return __builtin_nontemporal_load((const f32x4*)p); }
__device__ __forceinline__ void  nts1(float* p, float v) { __builtin_nontemporal_store(v, p); }
__device__ __forceinline__ void  nts4(float* p, f32x4 v) { __builtin_nontemporal_store(v, (f32x4*)p); }

// ---------------------------------------------------------------------------
// Kernel T: K [bh][64][2048] -> kT [bh][2048][64] bf16 ; V [bh][2048][64] ->
// vT [bh][64][2048] bf16. Fully coalesced both sides.
// ---------------------------------------------------------------------------
__global__ __launch_bounds__(256) void transpose_kernel(
    const float* __restrict__ kin, const float* __restrict__ vin,
    unsigned short* __restrict__ kT, unsigned short* __restrict__ vT)
{
  __shared__ float tile[64][65];
  const int bh = blockIdx.y;
  const int bx = blockIdx.x;
  const int t  = threadIdx.x;

  if (blockIdx.z == 0) {
    const float* in = kin + (size_t)bh * D_HEAD * S_LEN;
    #pragma unroll
    for (int p = 0; p < 4; ++p) {
      const int row = p * 16 + (t >> 4);
      f32x4 f = ntl4(in + (size_t)row * S_LEN + bx * 64 + (t & 15) * 4);
      tile[row][(t & 15) * 4 + 0] = f.x; tile[row][(t & 15) * 4 + 1] = f.y;
      tile[row][(t & 15) * 4 + 2] = f.z; tile[row][(t & 15) * 4 + 3] = f.w;
    }
    __syncthreads();
    union { unsigned short h[16]; uint4 q[2]; } u;
    #pragma unroll
    for (int i = 0; i < 16; ++i) u.h[i] = (unsigned short)f2bf(tile[(t & 3) * 16 + i][t >> 2]);
    uint4* dst = (uint4*)(kT + (size_t)bh * S_LEN * D_HEAD
                             + (size_t)(bx * 64 + (t >> 2)) * D_HEAD + (t & 3) * 16);
    dst[0] = u.q[0]; dst[1] = u.q[1];
  } else {
    const float* in = vin + (size_t)bh * S_LEN * D_HEAD;
    #pragma unroll
    for (int p = 0; p < 4; ++p) {
      const int row = p * 16 + (t >> 4);
      f32x4 f = ntl4(in + (size_t)(bx * 64 + row) * D_HEAD + (t & 15) * 4);
      tile[row][(t & 15) * 4 + 0] = f.x; tile[row][(t & 15) * 4 + 1] = f.y;
      tile[row][(t & 15) * 4 + 2] = f.z; tile[row][(t & 15) * 4 + 3] = f.w;
    }
    __syncthreads();
    union { unsigned short h[16]; uint4 q[2]; } u;
    #pragma unroll
    for (int i = 0; i < 16; ++i) u.h[i] = (unsigned short)f2bf(tile[(t & 3) * 16 + i][t >> 2]);
    uint4* dst = (uint4*)(vT + (size_t)bh * D_HEAD * S_LEN
                             + (size_t)(t >> 2) * S_LEN + bx * 64 + (t & 3) * 16);
    dst[0] = u.q[0]; dst[1] = u.q[1];
  }
}

// ---------------------------------------------------------------------------
// Fused kernel: one 16-row strip per block (256 thr, 4 waves, col-split 512).
//  P1 : s = QK^T*scale+prev -> NT f32 store + bf16 LDS stash + row-sum l
//  P2a: coalesced LDS pass -> weights = exp(s)/l NT f32 store; bf16(w) -> LDS
//  P2b: PV MFMA (A = w from LDS, B = vT) -> merge 4 waves -> NT O store
// Scores never re-read from HBM. 16x16x32 MFMA; layouts as verified in R0.
// ---------------------------------------------------------------------------
__global__ __launch_bounds__(256, 2) void fused_kernel(
    const float* __restrict__ q, const unsigned short* __restrict__ kT,
    const float* __restrict__ prev, const float* __restrict__ scale_p,
    const unsigned short* __restrict__ vT,
    float* __restrict__ scores, float* __restrict__ weights, float* __restrict__ outO)
{
  __shared__ union {
    unsigned short s[16][SPAD];   // 65664 B
    float om[4][16][68];          // 17408 B (aliased after P2b barrier)
  } sh;
  __shared__ float lred[4][16];
  __shared__ float rlv[16];

  const int bh   = blockIdx.y;
  const int m0   = blockIdx.x * 16;
  const int tid  = threadIdx.x;
  const int w    = tid >> 6;
  const int lane = tid & 63;
  const int lr   = lane & 15;
  const int lg   = lane >> 4;
  const float scale = scale_p[0];

  // Q A-frags: row = m0+lr, k elem j of chunk kk -> d = kk*32 + lg*8 + j
  short8 aq[2];
  {
    const float* qrow = q + ((size_t)bh * S_LEN + m0 + lr) * D_HEAD;
    #pragma unroll
    for (int kk = 0; kk < 2; ++kk) {
      f32x4 f0 = *(const f32x4*)(qrow + kk * 32 + lg * 8);
      f32x4 f1 = *(const f32x4*)(qrow + kk * 32 + lg * 8 + 4);
      short8 a;
      a[0]=f2bf(f0.x); a[1]=f2bf(f0.y); a[2]=f2bf(f0.z); a[3]=f2bf(f0.w);
      a[4]=f2bf(f1.x); a[5]=f2bf(f1.y); a[6]=f2bf(f1.z); a[7]=f2bf(f1.w);
      aq[kk] = a;
    }
  }

  const unsigned short* kbase = kT + (size_t)bh * S_LEN * D_HEAD;
  const float* prow = prev   + (size_t)bh * S_LEN * S_LEN;
  float*       srow = scores + (size_t)bh * S_LEN * S_LEN;

  float ls[4] = {0.f, 0.f, 0.f, 0.f};

  // ---------------- Phase 1 ----------------
  for (int t8 = 0; t8 < 8; ++t8) {
    const int n0 = w * 512 + t8 * 64;
    f32x4 acc[4];
    #pragma unroll
    for (int nt = 0; nt < 4; ++nt) acc[nt] = (f32x4){0.f, 0.f, 0.f, 0.f};

    #pragma unroll
    for (int kk = 0; kk < 2; ++kk) {
      #pragma unroll
      for (int nt = 0; nt < 4; ++nt) {
        const short8 b = *(const short8*)(
            kbase + (size_t)(n0 + nt * 16 + lr) * D_HEAD + kk * 32 + lg * 8);
        acc[nt] = __builtin_amdgcn_mfma_f32_16x16x32_bf16(aq[kk], b, acc[nt], 0, 0, 0);
      }
    }

    #pragma unroll
    for (int nt = 0; nt < 4; ++nt) {
      const int col = n0 + nt * 16 + lr;
      #pragma unroll
      for (int rg = 0; rg < 4; ++rg) {
        const int rloc = lg * 4 + rg;                 // C row = (lane>>4)*4+reg
        const size_t g = (size_t)(m0 + rloc) * S_LEN + col;
        const float sv = acc[nt][rg] * scale + ntl(prow + g);
        nts1(srow + g, sv);
        sh.s[rloc][col] = (unsigned short)f2bf(sv);
        ls[rg] += __expf(sv);
      }
    }
  }

  // reduce l: over 16 lanes of each lg group (masks 1..8 stay in-group)
  #pragma unroll
  for (int rg = 0; rg < 4; ++rg) {
    #pragma unroll
    for (int msk = 1; msk <= 8; msk <<= 1)
      ls[rg] += __shfl_xor(ls[rg], msk, 64);
  }
  if (lr == 0) {
    #pragma unroll
    for (int rg = 0; rg < 4; ++rg) lred[w][lg * 4 + rg] = ls[rg];
  }
  __syncthreads();
  if (tid < 16)
    rlv[tid] = 1.0f / (lred[0][tid] + lred[1][tid] + lred[2][tid] + lred[3][tid]);
  __syncthreads();

  // ---------------- Phase 2a: weights out + bf16(w) back into LDS ----------
  {
    const int rloc = tid >> 4;
    const int cb   = (tid & 15) * 8;
    const float rl = rlv[rloc];
    float* wrow = weights + (size_t)bh * S_LEN * S_LEN + (size_t)(m0 + rloc) * S_LEN;
    for (int u = 0; u < 16; ++u) {
      const int c = cb + u * 128;
      short4v h0 = *(const short4v*)&sh.s[rloc][c];
      short4v h1 = *(const short4v*)&sh.s[rloc][c + 4];
      float e[8];
      e[0] = __expf(bf2f((unsigned short)h0[0])) * rl;
      e[1] = __expf(bf2f((unsigned short)h0[1])) * rl;
      e[2] = __expf(bf2f((unsigned short)h0[2])) * rl;
      e[3] = __expf(bf2f((unsigned short)h0[3])) * rl;
      e[4] = __expf(bf2f((unsigned short)h1[0])) * rl;
      e[5] = __expf(bf2f((unsigned short)h1[1])) * rl;
      e[6] = __expf(bf2f((unsigned short)h1[2])) * rl;
      e[7] = __expf(bf2f((unsigned short)h1[3])) * rl;
      nts4(wrow + c,     (f32x4){e[0], e[1], e[2], e[3]});
      nts4(wrow + c + 4, (f32x4){e[4], e[5], e[6], e[7]});
      short4v g0, g1;
      g0[0]=f2bf(e[0]); g0[1]=f2bf(e[1]); g0[2]=f2bf(e[2]); g0[3]=f2bf(e[3]);
      g1[0]=f2bf(e[4]); g1[1]=f2bf(e[5]); g1[2]=f2bf(e[6]); g1[3]=f2bf(e[7]);
      *(short4v*)&sh.s[rloc][c]     = g0;
      *(short4v*)&sh.s[rloc][c + 4] = g1;
    }
  }
  __syncthreads();

  // ---------------- Phase 2b: PV MFMA ----------------
  const unsigned short* vbase = vT + (size_t)bh * D_HEAD * S_LEN;
  f32x4 accp[4];
  #pragma unroll
  for (int ct = 0; ct < 4; ++ct) accp[ct] = (f32x4){0.f, 0.f, 0.f, 0.f};

  for (int kk = 0; kk < 16; ++kk) {
    const int c = w * 512 + kk * 32 + lg * 8;   // k = s offset; A row = lr
    short4v h0 = *(const short4v*)&sh.s[lr][c];
    short4v h1 = *(const short4v*)&sh.s[lr][c + 4];
    short8 a;
    a[0]=h0[0]; a[1]=h0[1]; a[2]=h0[2]; a[3]=h0[3];
    a[4]=h1[0]; a[5]=h1[1]; a[6]=h1[2]; a[7]=h1[3];
    #pragma unroll
    for (int ct = 0; ct < 4; ++ct) {
      const short8 b = *(const short8*)(
          vbase + (size_t)(ct * 16 + lr) * S_LEN + c);
      accp[ct] = __builtin_amdgcn_mfma_f32_16x16x32_bf16(a, b, accp[ct], 0, 0, 0);
    }
  }
  __syncthreads();   // all LDS w-reads done; safe to alias sh.om

  #pragma unroll
  for (int ct = 0; ct < 4; ++ct) {
    #pragma unroll
    for (int rg = 0; rg < 4; ++rg)
      sh.om[w][lg * 4 + rg][ct * 16 + lr] = accp[ct][rg];
  }
  __syncthreads();

  {
    const int rloc = tid >> 4;
    const int d4   = (tid & 15) * 4;
    f32x4 v;
    #pragma unroll
    for (int i = 0; i < 4; ++i)
      v[i] = sh.om[0][rloc][d4 + i] + sh.om[1][rloc][d4 + i]
           + sh.om[2][rloc][d4 + i] + sh.om[3][rloc][d4 + i];
    nts4(outO + ((size_t)bh * S_LEN + m0 + rloc) * D_HEAD + d4, v);
  }
}

// ---------------------------------------------------------------------------
extern "C" void kernel_launch(void* const* d_in, const int* in_sizes, int n_in,
                              void* d_out, int out_size, void* d_ws, size_t ws_size,
                              hipStream_t stream)
{
  const float* q     = (const float*)d_in[0];
  const float* kin   = (const float*)d_in[1];
  const float* vin   = (const float*)d_in[2];
  const float* prev  = (const float*)d_in[3];
  const float* scale = (const float*)d_in[4];

  float* O  = (float*)d_out;                                  // [32][2048][64]
  float* W  = O + (size_t)BH * S_LEN * D_HEAD;                // [32][2048][2048]
  float* Sc = W + (size_t)BH * S_LEN * S_LEN;                 // [32][2048][2048]

  unsigned short* kT = (unsigned short*)d_ws;                 // [32][2048][64] bf16
  unsigned short* vT = kT + (size_t)BH * S_LEN * D_HEAD;      // [32][64][2048] bf16

  dim3 tgrid(S_LEN / 64, BH, 2);
  hipLaunchKernelGGL(transpose_kernel, tgrid, dim3(256), 0, stream, kin, vin, kT, vT);

  dim3 grid(S_LEN / 16, BH);
  hipLaunchKernelGGL(fused_kernel, grid, dim3(256), 0, stream,
                     q, kT, prev, scale, vT, Sc, W, O);
}

// Round 6
// 544.410 us; speedup vs baseline: 1.6778x; 1.0397x over previous
//
#include <hip/hip_runtime.h>
#include <math.h>

// Problem dims
#define S_LEN 2048
#define D_HEAD 64
#define BH 32

typedef __attribute__((ext_vector_type(8))) short short8;    // 8 bf16 (4 VGPR)
typedef __attribute__((ext_vector_type(4))) short short4v;   // 8B LDS chunk
typedef __attribute__((ext_vector_type(4))) float f32x4;

// LDS row stride in bf16 elems: 4104B rows -> 8B aligned (b64 ok), bank offset
// 2 per row -> P1's 4-row scatter covers all 32 banks at 2-way (free).
#define SPAD 2052

__device__ __forceinline__ short f2bf(float f) {
  union { float f; unsigned u; } a; a.f = f;
  unsigned u = a.u;
  unsigned r = (u + 0x7fffu + ((u >> 16) & 1u)) >> 16;   // RNE, no NaNs here
  return (short)r;
}
__device__ __forceinline__ float bf2f(unsigned short h) {
  union { unsigned u; float f; } a; a.u = ((unsigned)h) << 16; return a.f;
}
__device__ __forceinline__ f32x4 ntl4(const float* p) { return __builtin_nontemporal_load((const f32x4*)p); }
__device__ __forceinline__ void  nts4(float* p, f32x4 v) { __builtin_nontemporal_store(v, (f32x4*)p); }

// ---------------------------------------------------------------------------
// Kernel T: K [bh][64][2048] -> kT [bh][2048][64] bf16 ; V [bh][2048][64] ->
// vT [bh][64][2048] bf16. Fully coalesced both sides.
// ---------------------------------------------------------------------------
__global__ __launch_bounds__(256) void transpose_kernel(
    const float* __restrict__ kin, const float* __restrict__ vin,
    unsigned short* __restrict__ kT, unsigned short* __restrict__ vT)
{
  __shared__ float tile[64][65];
  const int bh = blockIdx.y;
  const int bx = blockIdx.x;
  const int t  = threadIdx.x;

  if (blockIdx.z == 0) {
    const float* in = kin + (size_t)bh * D_HEAD * S_LEN;
    #pragma unroll
    for (int p = 0; p < 4; ++p) {
      const int row = p * 16 + (t >> 4);
      f32x4 f = ntl4(in + (size_t)row * S_LEN + bx * 64 + (t & 15) * 4);
      tile[row][(t & 15) * 4 + 0] = f.x; tile[row][(t & 15) * 4 + 1] = f.y;
      tile[row][(t & 15) * 4 + 2] = f.z; tile[row][(t & 15) * 4 + 3] = f.w;
    }
    __syncthreads();
    union { unsigned short h[16]; uint4 q[2]; } u;
    #pragma unroll
    for (int i = 0; i < 16; ++i) u.h[i] = (unsigned short)f2bf(tile[(t & 3) * 16 + i][t >> 2]);
    uint4* dst = (uint4*)(kT + (size_t)bh * S_LEN * D_HEAD
                             + (size_t)(bx * 64 + (t >> 2)) * D_HEAD + (t & 3) * 16);
    dst[0] = u.q[0]; dst[1] = u.q[1];
  } else {
    const float* in = vin + (size_t)bh * S_LEN * D_HEAD;
    #pragma unroll
    for (int p = 0; p < 4; ++p) {
      const int row = p * 16 + (t >> 4);
      f32x4 f = ntl4(in + (size_t)(bx * 64 + row) * D_HEAD + (t & 15) * 4);
      tile[row][(t & 15) * 4 + 0] = f.x; tile[row][(t & 15) * 4 + 1] = f.y;
      tile[row][(t & 15) * 4 + 2] = f.z; tile[row][(t & 15) * 4 + 3] = f.w;
    }
    __syncthreads();
    union { unsigned short h[16]; uint4 q[2]; } u;
    #pragma unroll
    for (int i = 0; i < 16; ++i) u.h[i] = (unsigned short)f2bf(tile[(t & 3) * 16 + i][t >> 2]);
    uint4* dst = (uint4*)(vT + (size_t)bh * D_HEAD * S_LEN
                             + (size_t)(t >> 2) * S_LEN + bx * 64 + (t & 3) * 16);
    dst[0] = u.q[0]; dst[1] = u.q[1];
  }
}

// ---------------------------------------------------------------------------
// Fused kernel, 16-row strip per block (4 waves, col-split 512 in MFMA phases).
//  P1 : QK^T MFMA -> bf16(acc) into LDS (C-layout scatter, LDS-only)
//  P2 : coalesced pass (thread = row x 8-col chunks): prev NT float4 load,
//       sv = qk*scale+prev, scores NT float4 store, exp-sum, bf16(sv)->LDS.
//       Row owned by 16 lanes of ONE wave -> l reduce = 4 shfl_xor, no barrier.
//  P3 : same mapping: w = exp(sv)*rl, weights NT float4 store, bf16(w)->LDS.
//  P4 : PV MFMA (A from LDS, B = vT via L2) -> merge 4 waves -> O NT store.
// All HBM traffic is 16B/lane vectorized non-temporal.
// ---------------------------------------------------------------------------
__global__ __launch_bounds__(256, 2) void fused_kernel(
    const float* __restrict__ q, const unsigned short* __restrict__ kT,
    const float* __restrict__ prev, const float* __restrict__ scale_p,
    const unsigned short* __restrict__ vT,
    float* __restrict__ scores, float* __restrict__ weights, float* __restrict__ outO)
{
  __shared__ union {
    unsigned short s[16][SPAD];   // 65664 B
    float om[4][16][68];          // aliased after P4 barrier
  } sh;

  const int bh   = blockIdx.y;
  const int m0   = blockIdx.x * 16;
  const int tid  = threadIdx.x;
  const int w    = tid >> 6;
  const int lane = tid & 63;
  const int lr   = lane & 15;
  const int lg   = lane >> 4;
  const float scale = scale_p[0];

  // Q A-frags: row = m0+lr, k elem j of chunk kk -> d = kk*32 + lg*8 + j
  short8 aq[2];
  {
    const float* qrow = q + ((size_t)bh * S_LEN + m0 + lr) * D_HEAD;
    #pragma unroll
    for (int kk = 0; kk < 2; ++kk) {
      f32x4 f0 = *(const f32x4*)(qrow + kk * 32 + lg * 8);
      f32x4 f1 = *(const f32x4*)(qrow + kk * 32 + lg * 8 + 4);
      short8 a;
      a[0]=f2bf(f0.x); a[1]=f2bf(f0.y); a[2]=f2bf(f0.z); a[3]=f2bf(f0.w);
      a[4]=f2bf(f1.x); a[5]=f2bf(f1.y); a[6]=f2bf(f1.z); a[7]=f2bf(f1.w);
      aq[kk] = a;
    }
  }

  const unsigned short* kbase = kT + (size_t)bh * S_LEN * D_HEAD;

  // ---------------- P1: QK^T -> LDS (bf16 raw products) ----------------
  for (int t8 = 0; t8 < 8; ++t8) {
    const int n0 = w * 512 + t8 * 64;
    f32x4 acc[4];
    #pragma unroll
    for (int nt = 0; nt < 4; ++nt) acc[nt] = (f32x4){0.f, 0.f, 0.f, 0.f};

    #pragma unroll
    for (int kk = 0; kk < 2; ++kk) {
      #pragma unroll
      for (int nt = 0; nt < 4; ++nt) {
        const short8 b = *(const short8*)(
            kbase + (size_t)(n0 + nt * 16 + lr) * D_HEAD + kk * 32 + lg * 8);
        acc[nt] = __builtin_amdgcn_mfma_f32_16x16x32_bf16(aq[kk], b, acc[nt], 0, 0, 0);
      }
    }
    #pragma unroll
    for (int nt = 0; nt < 4; ++nt)
      #pragma unroll
      for (int rg = 0; rg < 4; ++rg)
        sh.s[lg * 4 + rg][n0 + nt * 16 + lr] = (unsigned short)f2bf(acc[nt][rg]);
  }
  __syncthreads();

  // ---------------- P2: coalesced scores + row-sum ----------------
  const int rloc = tid >> 4;        // row (16 lanes of one wave per row)
  const int cb   = (tid & 15) * 8;  // col chunk base
  const size_t rowoff = (size_t)bh * S_LEN * S_LEN + (size_t)(m0 + rloc) * S_LEN;
  const float* prevrow = prev + rowoff;
  float*       srow    = scores + rowoff;
  float sum = 0.f;

  for (int u = 0; u < 16; ++u) {
    const int c = cb + u * 128;
    short4v h0 = *(const short4v*)&sh.s[rloc][c];
    short4v h1 = *(const short4v*)&sh.s[rloc][c + 4];
    f32x4 p0 = ntl4(prevrow + c);
    f32x4 p1 = ntl4(prevrow + c + 4);
    f32x4 s0, s1;
    s0.x = bf2f((unsigned short)h0[0]) * scale + p0.x;
    s0.y = bf2f((unsigned short)h0[1]) * scale + p0.y;
    s0.z = bf2f((unsigned short)h0[2]) * scale + p0.z;
    s0.w = bf2f((unsigned short)h0[3]) * scale + p0.w;
    s1.x = bf2f((unsigned short)h1[0]) * scale + p1.x;
    s1.y = bf2f((unsigned short)h1[1]) * scale + p1.y;
    s1.z = bf2f((unsigned short)h1[2]) * scale + p1.z;
    s1.w = bf2f((unsigned short)h1[3]) * scale + p1.w;
    nts4(srow + c,     s0);
    nts4(srow + c + 4, s1);
    sum += __expf(s0.x) + __expf(s0.y) + __expf(s0.z) + __expf(s0.w)
         + __expf(s1.x) + __expf(s1.y) + __expf(s1.z) + __expf(s1.w);
    short4v g0, g1;
    g0[0]=f2bf(s0.x); g0[1]=f2bf(s0.y); g0[2]=f2bf(s0.z); g0[3]=f2bf(s0.w);
    g1[0]=f2bf(s1.x); g1[1]=f2bf(s1.y); g1[2]=f2bf(s1.z); g1[3]=f2bf(s1.w);
    *(short4v*)&sh.s[rloc][c]     = g0;
    *(short4v*)&sh.s[rloc][c + 4] = g1;
  }

  // row-sum across the 16 lanes owning this row (same wave, aligned group)
  #pragma unroll
  for (int msk = 1; msk <= 8; msk <<= 1)
    sum += __shfl_xor(sum, msk, 64);
  const float rl = 1.0f / sum;

  // ---------------- P3: weights (reads only this thread's own LDS) --------
  float* wrow = weights + rowoff;
  for (int u = 0; u < 16; ++u) {
    const int c = cb + u * 128;
    short4v h0 = *(const short4v*)&sh.s[rloc][c];
    short4v h1 = *(const short4v*)&sh.s[rloc][c + 4];
    f32x4 e0, e1;
    e0.x = __expf(bf2f((unsigned short)h0[0])) * rl;
    e0.y = __expf(bf2f((unsigned short)h0[1])) * rl;
    e0.z = __expf(bf2f((unsigned short)h0[2])) * rl;
    e0.w = __expf(bf2f((unsigned short)h0[3])) * rl;
    e1.x = __expf(bf2f((unsigned short)h1[0])) * rl;
    e1.y = __expf(bf2f((unsigned short)h1[1])) * rl;
    e1.z = __expf(bf2f((unsigned short)h1[2])) * rl;
    e1.w = __expf(bf2f((unsigned short)h1[3])) * rl;
    nts4(wrow + c,     e0);
    nts4(wrow + c + 4, e1);
    short4v g0, g1;
    g0[0]=f2bf(e0.x); g0[1]=f2bf(e0.y); g0[2]=f2bf(e0.z); g0[3]=f2bf(e0.w);
    g1[0]=f2bf(e1.x); g1[1]=f2bf(e1.y); g1[2]=f2bf(e1.z); g1[3]=f2bf(e1.w);
    *(short4v*)&sh.s[rloc][c]     = g0;
    *(short4v*)&sh.s[rloc][c + 4] = g1;
  }
  __syncthreads();

  // ---------------- P4: PV MFMA ----------------
  const unsigned short* vbase = vT + (size_t)bh * D_HEAD * S_LEN;
  f32x4 accp[4];
  #pragma unroll
  for (int ct = 0; ct < 4; ++ct) accp[ct] = (f32x4){0.f, 0.f, 0.f, 0.f};

  for (int kk = 0; kk < 16; ++kk) {
    const int c = w * 512 + kk * 32 + lg * 8;   // k offset; A row = lr
    short4v h0 = *(const short4v*)&sh.s[lr][c];
    short4v h1 = *(const short4v*)&sh.s[lr][c + 4];
    short8 a;
    a[0]=h0[0]; a[1]=h0[1]; a[2]=h0[2]; a[3]=h0[3];
    a[4]=h1[0]; a[5]=h1[1]; a[6]=h1[2]; a[7]=h1[3];
    #pragma unroll
    for (int ct = 0; ct < 4; ++ct) {
      const short8 b = *(const short8*)(vbase + (size_t)(ct * 16 + lr) * S_LEN + c);
      accp[ct] = __builtin_amdgcn_mfma_f32_16x16x32_bf16(a, b, accp[ct], 0, 0, 0);
    }
  }
  __syncthreads();   // all LDS reads done; safe to alias sh.om

  #pragma unroll
  for (int ct = 0; ct < 4; ++ct)
    #pragma unroll
    for (int rg = 0; rg < 4; ++rg)
      sh.om[w][lg * 4 + rg][ct * 16 + lr] = accp[ct][rg];
  __syncthreads();

  {
    const int d4 = (tid & 15) * 4;
    f32x4 v;
    #pragma unroll
    for (int i = 0; i < 4; ++i)
      v[i] = sh.om[0][rloc][d4 + i] + sh.om[1][rloc][d4 + i]
           + sh.om[2][rloc][d4 + i] + sh.om[3][rloc][d4 + i];
    nts4(outO + ((size_t)bh * S_LEN + m0 + rloc) * D_HEAD + d4, v);
  }
}

// ---------------------------------------------------------------------------
extern "C" void kernel_launch(void* const* d_in, const int* in_sizes, int n_in,
                              void* d_out, int out_size, void* d_ws, size_t ws_size,
                              hipStream_t stream)
{
  const float* q     = (const float*)d_in[0];
  const float* kin   = (const float*)d_in[1];
  const float* vin   = (const float*)d_in[2];
  const float* prev  = (const float*)d_in[3];
  const float* scale = (const float*)d_in[4];

  float* O  = (float*)d_out;                                  // [32][2048][64]
  float* W  = O + (size_t)BH * S_LEN * D_HEAD;                // [32][2048][2048]
  float* Sc = W + (size_t)BH * S_LEN * S_LEN;                 // [32][2048][2048]

  unsigned short* kT = (unsigned short*)d_ws;                 // [32][2048][64] bf16
  unsigned short* vT = kT + (size_t)BH * S_LEN * D_HEAD;      // [32][64][2048] bf16

  dim3 tgrid(S_LEN / 64, BH, 2);
  hipLaunchKernelGGL(transpose_kernel, tgrid, dim3(256), 0, stream, kin, vin, kT, vT);

  dim3 grid(S_LEN / 16, BH);
  hipLaunchKernelGGL(fused_kernel, grid, dim3(256), 0, stream,
                     q, kT, prev, scale, vT, Sc, W, O);
}